// Round 3
// baseline (795.472 us; speedup 1.0000x reference)
//
#include <hip/hip_runtime.h>

#define N_NODES 50000
#define N_EDGES 500000
#define D 256
#define TWO_D 512

typedef __attribute__((ext_vector_type(8))) __bf16 bf16x8;
typedef __attribute__((ext_vector_type(4))) float f32x4;
typedef unsigned short ushort_t;

__device__ __forceinline__ unsigned short f2bf(float f) {
    unsigned int u = __builtin_bit_cast(unsigned int, f);
    u += 0x7FFFu + ((u >> 16) & 1u);   // round-to-nearest-even
    return (unsigned short)(u >> 16);
}
__device__ __forceinline__ unsigned int pk2(float lo, float hi) {
    return (unsigned int)f2bf(lo) | ((unsigned int)f2bf(hi) << 16);
}
__device__ __forceinline__ float bf2f(ushort_t u) {
    return __builtin_bit_cast(float, ((unsigned int)u) << 16);
}

// ---------------- prep kernels ----------------

__global__ void k_zero(float* __restrict__ p, int n4) {
    int i = blockIdx.x * blockDim.x + threadIdx.x;
    if (i < n4) ((float4*)p)[i] = make_float4(0.f, 0.f, 0.f, 0.f);
}

__global__ void k_cvt_x(const float* __restrict__ x, ushort_t* __restrict__ xb, int n8) {
    int i = blockIdx.x * blockDim.x + threadIdx.x;
    if (i < n8) {
        const float4* s = (const float4*)(x + (size_t)i * 8);
        float4 a = s[0], b = s[1];
        uint4 o;
        o.x = pk2(a.x, a.y); o.y = pk2(a.z, a.w);
        o.z = pk2(b.x, b.y); o.w = pk2(b.z, b.w);
        *(uint4*)(xb + (size_t)i * 8) = o;
    }
}

// W slice [KW rows of D cols] f32 -> Wt [D][KW] bf16 (transposed)
__global__ void k_wt(const float* __restrict__ w, ushort_t* __restrict__ wt, int KW) {
    int n = blockIdx.x;
    for (int k = threadIdx.x; k < KW; k += blockDim.x)
        wt[(size_t)n * KW + k] = f2bf(w[(size_t)k * D + n]);
}

__global__ void k_count_i(const int* __restrict__ coli, int* __restrict__ cnt) {
    int e = blockIdx.x * blockDim.x + threadIdx.x;
    if (e < N_EDGES) atomicAdd(&cnt[coli[e]], 1);
}

// ---------------- CSR build ----------------

__device__ __forceinline__ int iscan_block(int v, int tid) {
    int lane = tid & 63, wv = tid >> 6;
    int s = v;
    #pragma unroll
    for (int off = 1; off < 64; off <<= 1) {
        int t = __shfl_up(s, off, 64);
        if (lane >= off) s += t;
    }
    __shared__ int wsum[4];
    if (lane == 63) wsum[wv] = s;
    __syncthreads();
    #pragma unroll
    for (int w = 0; w < 3; ++w)
        if (wv > w) s += wsum[w];
    return s;
}

__global__ void k_scan_a(const int* __restrict__ cnt, int* __restrict__ rowptr,
                         int* __restrict__ bsum) {
    int i = blockIdx.x * 256 + threadIdx.x;
    int v = (i < N_NODES) ? cnt[i] : 0;
    int s = iscan_block(v, threadIdx.x);
    if (i < N_NODES) rowptr[i] = s - v;
    if (threadIdx.x == 255) bsum[blockIdx.x] = s;
}

__global__ void k_scan_b(int* __restrict__ bsum, int nb) {
    int i = threadIdx.x;
    int v = (i < nb) ? bsum[i] : 0;
    int s = iscan_block(v, i);
    if (i < nb) bsum[i] = s - v;
}

__global__ void k_scan_c(int* __restrict__ rowptr, const int* __restrict__ bsum,
                         int* __restrict__ cursor) {
    int i = blockIdx.x * 256 + threadIdx.x;
    if (i < N_NODES) {
        int r = rowptr[i] + bsum[blockIdx.x];
        rowptr[i] = r;
        cursor[i] = r;
    }
    if (i == 0) rowptr[N_NODES] = N_EDGES;
}

__global__ void k_fill(const int* __restrict__ coli, const int* __restrict__ rowi,
                       int* __restrict__ cursor, int* __restrict__ elist,
                       int* __restrict__ rowg) {
    int e = blockIdx.x * blockDim.x + threadIdx.x;
    if (e < N_EDGES) {
        int p = atomicAdd(&cursor[coli[e]], 1);
        elist[p] = e;
        rowg[p] = rowi[e];
    }
}

// CSR position -> destination node (binary search over rowptr)
__global__ void k_posnode(const int* __restrict__ rowptr, int* __restrict__ posnode) {
    int p = blockIdx.x * blockDim.x + threadIdx.x;
    if (p >= N_EDGES) return;
    int lo = 0, hi = N_NODES;
    while (hi - lo > 1) {
        int mid = (lo + hi) >> 1;
        if (rowptr[mid] <= p) lo = mid; else hi = mid;
    }
    posnode[p] = lo;
}

// ---------------- xw1 = x @ W1a + b1 (f32 out, per node) ----------------
__global__ __launch_bounds__(256) void k_xw1(
    const ushort_t* __restrict__ xb, const ushort_t* __restrict__ w1at,
    const float* __restrict__ b1, float* __restrict__ xw1)
{
    __shared__ __align__(16) ushort_t As[64 * 64];
    __shared__ __align__(16) ushort_t Bs[256 * 64];
    const int tid = threadIdx.x;
    const int wave = tid >> 6, lane = tid & 63;
    const int lr = lane & 15, lh = lane >> 4;
    const int n0 = blockIdx.x * 64;

    const int sm = tid >> 2;
    const int sc = (tid & 3) << 4;
    int ns = n0 + sm; if (ns >= N_NODES) ns = N_NODES - 1;
    const ushort_t* xrow = xb + (size_t)ns * D;
    const ushort_t* wrow = w1at + (size_t)tid * D;
    const int swA = (sm & 7) << 3;
    const int swB = (tid & 7) << 3;

    f32x4 acc[4][4];
    #pragma unroll
    for (int i = 0; i < 4; ++i)
        #pragma unroll
        for (int j = 0; j < 4; ++j)
            acc[i][j] = (f32x4){0.f, 0.f, 0.f, 0.f};

    for (int kk = 0; kk < 4; ++kk) {
        const int k0 = kk << 6;
        const uint4* sx = (const uint4*)(xrow + k0 + sc);
        uint4 av0 = sx[0], av1 = sx[1];
        const uint4* wsv = (const uint4*)(wrow + k0);
        uint4 w0 = wsv[0], w1 = wsv[1], w2 = wsv[2], w3 = wsv[3];
        uint4 w4 = wsv[4], w5 = wsv[5], w6 = wsv[6], w7 = wsv[7];

        __syncthreads();
        *(uint4*)&As[sm * 64 + ( sc      ^ swA)] = av0;
        *(uint4*)&As[sm * 64 + ((sc + 8) ^ swA)] = av1;
        {
            const int base = tid * 64;
            *(uint4*)&Bs[base + ( 0 ^ swB)] = w0;
            *(uint4*)&Bs[base + ( 8 ^ swB)] = w1;
            *(uint4*)&Bs[base + (16 ^ swB)] = w2;
            *(uint4*)&Bs[base + (24 ^ swB)] = w3;
            *(uint4*)&Bs[base + (32 ^ swB)] = w4;
            *(uint4*)&Bs[base + (40 ^ swB)] = w5;
            *(uint4*)&Bs[base + (48 ^ swB)] = w6;
            *(uint4*)&Bs[base + (56 ^ swB)] = w7;
        }
        __syncthreads();

        #pragma unroll
        for (int kh = 0; kh < 2; ++kh) {
            const int kb = kh * 32 + lh * 8;
            bf16x8 af[4], bfr[4];
            #pragma unroll
            for (int i = 0; i < 4; ++i) {
                int m = i * 16 + lr;
                af[i] = *(const bf16x8*)&As[m * 64 + (kb ^ ((m & 7) << 3))];
            }
            #pragma unroll
            for (int j = 0; j < 4; ++j) {
                int n = wave * 64 + j * 16 + lr;
                bfr[j] = *(const bf16x8*)&Bs[n * 64 + (kb ^ ((n & 7) << 3))];
            }
            #pragma unroll
            for (int i = 0; i < 4; ++i)
                #pragma unroll
                for (int j = 0; j < 4; ++j)
                    acc[i][j] = __builtin_amdgcn_mfma_f32_16x16x32_bf16(af[i], bfr[j], acc[i][j], 0, 0, 0);
        }
    }

    float bv[4];
    #pragma unroll
    for (int j = 0; j < 4; ++j) bv[j] = b1[wave * 64 + j * 16 + lr];
    #pragma unroll
    for (int i = 0; i < 4; ++i) {
        #pragma unroll
        for (int r = 0; r < 4; ++r) {
            int m = i * 16 + lh * 4 + r;
            int node = n0 + m;
            if (node < N_NODES) {
                float* orow = xw1 + (size_t)node * D;
                #pragma unroll
                for (int j = 0; j < 4; ++j)
                    orow[wave * 64 + j * 16 + lr] = acc[i][j][r] + bv[j];
            }
        }
    }
}

// ---------------- edge GEMM (K=256) + fused segmented aggregation ----------------
// processes CSR positions [p0, p0+64): e = elist[p]
// h[p] = relu( xw1[rowg[p]] + ea[e] @ W1b ); agg[node] += column-sums per segment
__global__ __launch_bounds__(256) void k_edge_csr(
    const float* __restrict__ ea, const ushort_t* __restrict__ w1bt,
    const float* __restrict__ xw1, const int* __restrict__ elist,
    const int* __restrict__ rowg, const int* __restrict__ posnode,
    const int* __restrict__ rowptr, float* __restrict__ agg)
{
    __shared__ __align__(16) ushort_t As[64 * 64];     // ea tile; reused as snd[64]
    __shared__ __align__(16) ushort_t Bs[256 * 64];    // W1b tile; reused as h-tile [64][256]
    const int tid = threadIdx.x;
    const int wave = tid >> 6, lane = tid & 63;
    const int lr = lane & 15, lh = lane >> 4;
    const int p0 = blockIdx.x * 64;

    const int sm = tid >> 2;
    const int sc = (tid & 3) << 4;
    int ps = p0 + sm; if (ps >= N_EDGES) ps = N_EDGES - 1;
    const int es = elist[ps];
    const float* earow = ea + (size_t)es * D;
    const ushort_t* wrow = w1bt + (size_t)tid * D;
    const int swA = (sm & 7) << 3;
    const int swB = (tid & 7) << 3;

    f32x4 acc[4][4];
    #pragma unroll
    for (int i = 0; i < 4; ++i)
        #pragma unroll
        for (int j = 0; j < 4; ++j)
            acc[i][j] = (f32x4){0.f, 0.f, 0.f, 0.f};

    #pragma unroll 1
    for (int kk = 0; kk < 4; ++kk) {
        const int k0 = kk << 6;
        const float4* s = (const float4*)(earow + k0 + sc);
        float4 f0 = s[0], f1 = s[1], f2 = s[2], f3 = s[3];
        uint4 av0, av1;
        av0.x = pk2(f0.x, f0.y); av0.y = pk2(f0.z, f0.w);
        av0.z = pk2(f1.x, f1.y); av0.w = pk2(f1.z, f1.w);
        av1.x = pk2(f2.x, f2.y); av1.y = pk2(f2.z, f2.w);
        av1.z = pk2(f3.x, f3.y); av1.w = pk2(f3.z, f3.w);
        const uint4* wsv = (const uint4*)(wrow + k0);
        uint4 w0 = wsv[0], w1 = wsv[1], w2 = wsv[2], w3 = wsv[3];
        uint4 w4 = wsv[4], w5 = wsv[5], w6 = wsv[6], w7 = wsv[7];

        __syncthreads();
        *(uint4*)&As[sm * 64 + ( sc      ^ swA)] = av0;
        *(uint4*)&As[sm * 64 + ((sc + 8) ^ swA)] = av1;
        {
            const int base = tid * 64;
            *(uint4*)&Bs[base + ( 0 ^ swB)] = w0;
            *(uint4*)&Bs[base + ( 8 ^ swB)] = w1;
            *(uint4*)&Bs[base + (16 ^ swB)] = w2;
            *(uint4*)&Bs[base + (24 ^ swB)] = w3;
            *(uint4*)&Bs[base + (32 ^ swB)] = w4;
            *(uint4*)&Bs[base + (40 ^ swB)] = w5;
            *(uint4*)&Bs[base + (48 ^ swB)] = w6;
            *(uint4*)&Bs[base + (56 ^ swB)] = w7;
        }
        __syncthreads();

        #pragma unroll
        for (int kh = 0; kh < 2; ++kh) {
            const int kb = kh * 32 + lh * 8;
            bf16x8 af[4], bfr[4];
            #pragma unroll
            for (int i = 0; i < 4; ++i) {
                int m = i * 16 + lr;
                af[i] = *(const bf16x8*)&As[m * 64 + (kb ^ ((m & 7) << 3))];
            }
            #pragma unroll
            for (int j = 0; j < 4; ++j) {
                int n = wave * 64 + j * 16 + lr;
                bfr[j] = *(const bf16x8*)&Bs[n * 64 + (kb ^ ((n & 7) << 3))];
            }
            #pragma unroll
            for (int i = 0; i < 4; ++i)
                #pragma unroll
                for (int j = 0; j < 4; ++j)
                    acc[i][j] = __builtin_amdgcn_mfma_f32_16x16x32_bf16(af[i], bfr[j], acc[i][j], 0, 0, 0);
        }
    }

    // ---- epilogue: add gathered xw1[row], relu, stash h-tile in LDS ----
    __syncthreads();                       // main-loop LDS reads complete
    int* snd = (int*)As;                   // [64] node id per tile row
    if (tid < 64) snd[tid] = posnode[min(p0 + tid, N_EDGES - 1)];

    #pragma unroll
    for (int i = 0; i < 4; ++i) {
        #pragma unroll
        for (int r = 0; r < 4; ++r) {
            const int m = i * 16 + lh * 4 + r;
            const int p = p0 + m;
            const bool ok = (p < N_EDGES);
            const int srow = ok ? rowg[p] : 0;       // broadcast per 16-lane group
            const float* xr = xw1 + (size_t)srow * D + wave * 64 + lr;
            #pragma unroll
            for (int j = 0; j < 4; ++j) {
                float v = ok ? (acc[i][j][r] + xr[j * 16]) : 0.f;
                v = v > 0.f ? v : 0.f;
                const int n = wave * 64 + j * 16 + lr;
                Bs[m * 256 + (n ^ (((m >> 2) & 3) << 2))] = f2bf(v);
            }
        }
    }
    __syncthreads();                       // snd + h-tile visible

    // ---- segmented column-sum: thread owns column c ----
    const int c = tid;
    int node = snd[0];
    float s = 0.f;
    #pragma unroll 1
    for (int rr = 0; rr < 64; rr += 8) {
        float v[8];
        int nd[8];
        #pragma unroll
        for (int q = 0; q < 8; ++q) {
            int r = rr + q;
            v[q] = bf2f(Bs[r * 256 + (c ^ (((r >> 2) & 3) << 2))]);
            nd[q] = snd[r];
        }
        #pragma unroll
        for (int q = 0; q < 8; ++q) {
            if (nd[q] != node) {               // wave-uniform branch
                float* dst = agg + (size_t)node * D + c;
                if (rowptr[node] >= p0 && rowptr[node + 1] <= p0 + 64) *dst = s;
                else atomicAdd(dst, s);
                node = nd[q];
                s = 0.f;
            }
            s += v[q];
        }
    }
    {
        float* dst = agg + (size_t)node * D + c;
        if (rowptr[node] >= p0 && rowptr[node + 1] <= p0 + 64) *dst = s;
        else atomicAdd(dst, s);
    }
}

// ---------------- node GEMM ----------------
// out[i][n] = relu( concat(x[i], agg[i]/max(cnt,1)) @ W2 + b2 )
__global__ __launch_bounds__(256) void k_node(
    const ushort_t* __restrict__ xb, const float* __restrict__ agg,
    const int* __restrict__ cnti,
    const ushort_t* __restrict__ w2t, const float* __restrict__ b2,
    float* __restrict__ out)
{
    __shared__ __align__(16) ushort_t As[64 * 64];
    __shared__ __align__(16) ushort_t Bs[256 * 64];
    const int tid = threadIdx.x;
    const int wave = tid >> 6, lane = tid & 63;
    const int lr = lane & 15, lh = lane >> 4;
    const int n0 = blockIdx.x * 64;

    const int sm = tid >> 2;
    const int sc = (tid & 3) << 4;
    int ns = n0 + sm; if (ns >= N_NODES) ns = N_NODES - 1;
    const ushort_t* xrow = xb + (size_t)ns * D;
    const float*    arow = agg + (size_t)ns * D;
    const float     ic   = 1.0f / fmaxf((float)cnti[ns], 1.0f);
    const ushort_t* wrow = w2t + (size_t)tid * TWO_D;
    const int swA = (sm & 7) << 3;
    const int swB = (tid & 7) << 3;

    f32x4 acc[4][4];
    #pragma unroll
    for (int i = 0; i < 4; ++i)
        #pragma unroll
        for (int j = 0; j < 4; ++j)
            acc[i][j] = (f32x4){0.f, 0.f, 0.f, 0.f};

    for (int kk = 0; kk < 8; ++kk) {
        const int k0 = kk << 6;
        uint4 av0, av1;
        if (kk < 4) {
            const uint4* s = (const uint4*)(xrow + k0 + sc);
            av0 = s[0]; av1 = s[1];
        } else {
            const float4* s = (const float4*)(arow + (k0 - D) + sc);
            float4 f0 = s[0], f1 = s[1], f2 = s[2], f3 = s[3];
            f0.x *= ic; f0.y *= ic; f0.z *= ic; f0.w *= ic;
            f1.x *= ic; f1.y *= ic; f1.z *= ic; f1.w *= ic;
            f2.x *= ic; f2.y *= ic; f2.z *= ic; f2.w *= ic;
            f3.x *= ic; f3.y *= ic; f3.z *= ic; f3.w *= ic;
            av0.x = pk2(f0.x, f0.y); av0.y = pk2(f0.z, f0.w);
            av0.z = pk2(f1.x, f1.y); av0.w = pk2(f1.z, f1.w);
            av1.x = pk2(f2.x, f2.y); av1.y = pk2(f2.z, f2.w);
            av1.z = pk2(f3.x, f3.y); av1.w = pk2(f3.z, f3.w);
        }
        const uint4* wsv = (const uint4*)(wrow + k0);
        uint4 w0 = wsv[0], w1 = wsv[1], w2 = wsv[2], w3 = wsv[3];
        uint4 w4 = wsv[4], w5 = wsv[5], w6 = wsv[6], w7 = wsv[7];

        __syncthreads();
        *(uint4*)&As[sm * 64 + ( sc      ^ swA)] = av0;
        *(uint4*)&As[sm * 64 + ((sc + 8) ^ swA)] = av1;
        {
            const int base = tid * 64;
            *(uint4*)&Bs[base + ( 0 ^ swB)] = w0;
            *(uint4*)&Bs[base + ( 8 ^ swB)] = w1;
            *(uint4*)&Bs[base + (16 ^ swB)] = w2;
            *(uint4*)&Bs[base + (24 ^ swB)] = w3;
            *(uint4*)&Bs[base + (32 ^ swB)] = w4;
            *(uint4*)&Bs[base + (40 ^ swB)] = w5;
            *(uint4*)&Bs[base + (48 ^ swB)] = w6;
            *(uint4*)&Bs[base + (56 ^ swB)] = w7;
        }
        __syncthreads();

        #pragma unroll
        for (int kh = 0; kh < 2; ++kh) {
            const int kb = kh * 32 + lh * 8;
            bf16x8 af[4], bfr[4];
            #pragma unroll
            for (int i = 0; i < 4; ++i) {
                int m = i * 16 + lr;
                af[i] = *(const bf16x8*)&As[m * 64 + (kb ^ ((m & 7) << 3))];
            }
            #pragma unroll
            for (int j = 0; j < 4; ++j) {
                int n = wave * 64 + j * 16 + lr;
                bfr[j] = *(const bf16x8*)&Bs[n * 64 + (kb ^ ((n & 7) << 3))];
            }
            #pragma unroll
            for (int i = 0; i < 4; ++i)
                #pragma unroll
                for (int j = 0; j < 4; ++j)
                    acc[i][j] = __builtin_amdgcn_mfma_f32_16x16x32_bf16(af[i], bfr[j], acc[i][j], 0, 0, 0);
        }
    }

    float bv[4];
    #pragma unroll
    for (int j = 0; j < 4; ++j) bv[j] = b2[wave * 64 + j * 16 + lr];
    #pragma unroll
    for (int i = 0; i < 4; ++i) {
        #pragma unroll
        for (int r = 0; r < 4; ++r) {
            int m = i * 16 + lh * 4 + r;
            int node = n0 + m;
            if (node < N_NODES) {
                float* orow = out + (size_t)node * D;
                #pragma unroll
                for (int j = 0; j < 4; ++j) {
                    float v = acc[i][j][r] + bv[j];
                    orow[wave * 64 + j * 16 + lr] = v > 0.f ? v : 0.f;
                }
            }
        }
    }
}

// ---------------- launch ----------------

extern "C" void kernel_launch(void* const* d_in, const int* in_sizes, int n_in,
                              void* d_out, int out_size, void* d_ws, size_t ws_size,
                              hipStream_t stream)
{
    const float* x  = (const float*)d_in[0];
    const int*   ei = (const int*)d_in[1];      // [2*E] int32: rows then cols
    const float* ea = (const float*)d_in[2];
    const float* W1 = (const float*)d_in[5];
    const float* b1 = (const float*)d_in[6];
    const float* W2 = (const float*)d_in[7];
    const float* b2 = (const float*)d_in[8];
    float* out = (float*)d_out;

    const int* rowi = ei;
    const int* coli = ei + N_EDGES;
    char* ws = (char*)d_ws;

    size_t off = 0;
    auto take = [&](size_t bytes) {
        char* p = ws + off;
        off = (off + bytes + 255) & ~(size_t)255;
        return p;
    };

    ushort_t* xb      = (ushort_t*)take((size_t)N_NODES * D * 2);
    ushort_t* w1at    = (ushort_t*)take((size_t)D * D * 2);
    ushort_t* w1bt    = (ushort_t*)take((size_t)D * D * 2);
    ushort_t* w2t     = (ushort_t*)take((size_t)D * TWO_D * 2);
    float*    xw1     = (float*)take((size_t)N_NODES * D * 4);
    float*    agg     = (float*)take((size_t)N_NODES * D * 4);
    int*      cnti    = (int*)take(50016 * 4);
    int*      rowptr  = (int*)take(50016 * 4);
    int*      cursor  = (int*)take(50016 * 4);
    int*      bsum    = (int*)take(256 * 4);
    int*      elist   = (int*)take((size_t)N_EDGES * 4);
    int*      rowg    = (int*)take((size_t)N_EDGES * 4);
    int*      posnode = (int*)take((size_t)N_EDGES * 4);

    const int NB = (N_NODES + 255) / 256;          // 196
    const int EB = (N_EDGES + 255) / 256;          // 1954
    const int NGB = (N_NODES + 63) / 64;           // 782
    const int EGB = (N_EDGES + 63) / 64;           // 7813

    k_cvt_x<<<(N_NODES * D / 8 + 255) / 256, 256, 0, stream>>>(x, xb, N_NODES * D / 8);
    k_wt   <<<D, 256, 0, stream>>>(W1, w1at, D);
    k_wt   <<<D, 256, 0, stream>>>(W1 + (size_t)D * D, w1bt, D);
    k_wt   <<<D, 256, 0, stream>>>(W2, w2t, TWO_D);

    k_zero   <<<49, 256, 0, stream>>>((float*)cnti, 50016 / 4);
    k_count_i<<<EB, 256, 0, stream>>>(coli, cnti);
    k_scan_a <<<NB, 256, 0, stream>>>(cnti, rowptr, bsum);
    k_scan_b <<<1, 256, 0, stream>>>(bsum, NB);
    k_scan_c <<<NB, 256, 0, stream>>>(rowptr, bsum, cursor);
    k_fill   <<<EB, 256, 0, stream>>>(coli, rowi, cursor, elist, rowg);
    k_posnode<<<EB, 256, 0, stream>>>(rowptr, posnode);

    k_xw1    <<<NGB, 256, 0, stream>>>(xb, w1at, b1, xw1);
    k_zero   <<<(N_NODES * D / 4 + 255) / 256, 256, 0, stream>>>(agg, N_NODES * D / 4);
    k_edge_csr<<<EGB, 256, 0, stream>>>(ea, w1bt, xw1, elist, rowg, posnode, rowptr, agg);
    k_node   <<<NGB, 256, 0, stream>>>(xb, agg, cnti, w2t, b2, out);
}

// Round 4
// 546.519 us; speedup vs baseline: 1.4555x; 1.4555x over previous
//
#include <hip/hip_runtime.h>

#define N_NODES 50000
#define N_EDGES 500000
#define D 256
#define TWO_D 512

typedef __attribute__((ext_vector_type(8))) __bf16 bf16x8;
typedef __attribute__((ext_vector_type(4))) float f32x4;
typedef unsigned short ushort_t;

__device__ __forceinline__ unsigned short f2bf(float f) {
    unsigned int u = __builtin_bit_cast(unsigned int, f);
    u += 0x7FFFu + ((u >> 16) & 1u);   // round-to-nearest-even
    return (unsigned short)(u >> 16);
}
__device__ __forceinline__ unsigned int pk2(float lo, float hi) {
    return (unsigned int)f2bf(lo) | ((unsigned int)f2bf(hi) << 16);
}

// ---------------- prep kernels ----------------

__global__ void k_zero(float* __restrict__ p, int n4) {
    int i = blockIdx.x * blockDim.x + threadIdx.x;
    if (i < n4) ((float4*)p)[i] = make_float4(0.f, 0.f, 0.f, 0.f);
}

__global__ void k_cvt_x(const float* __restrict__ x, ushort_t* __restrict__ xb, int n8) {
    int i = blockIdx.x * blockDim.x + threadIdx.x;
    if (i < n8) {
        const float4* s = (const float4*)(x + (size_t)i * 8);
        float4 a = s[0], b = s[1];
        uint4 o;
        o.x = pk2(a.x, a.y); o.y = pk2(a.z, a.w);
        o.z = pk2(b.x, b.y); o.w = pk2(b.z, b.w);
        *(uint4*)(xb + (size_t)i * 8) = o;
    }
}

// W slice [KW rows of D cols] f32 -> Wt [D][KW] bf16 (transposed)
__global__ void k_wt(const float* __restrict__ w, ushort_t* __restrict__ wt, int KW) {
    int n = blockIdx.x;
    for (int k = threadIdx.x; k < KW; k += blockDim.x)
        wt[(size_t)n * KW + k] = f2bf(w[(size_t)k * D + n]);
}

__global__ void k_count_i(const int* __restrict__ coli, int* __restrict__ cnt) {
    int e = blockIdx.x * blockDim.x + threadIdx.x;
    if (e < N_EDGES) atomicAdd(&cnt[coli[e]], 1);
}

// ---------------- CSR build ----------------

__device__ __forceinline__ int iscan_block(int v, int tid) {
    int lane = tid & 63, wv = tid >> 6;
    int s = v;
    #pragma unroll
    for (int off = 1; off < 64; off <<= 1) {
        int t = __shfl_up(s, off, 64);
        if (lane >= off) s += t;
    }
    __shared__ int wsum[4];
    if (lane == 63) wsum[wv] = s;
    __syncthreads();
    #pragma unroll
    for (int w = 0; w < 3; ++w)
        if (wv > w) s += wsum[w];
    return s;
}

__global__ void k_scan_a(const int* __restrict__ cnt, int* __restrict__ rowptr,
                         int* __restrict__ bsum) {
    int i = blockIdx.x * 256 + threadIdx.x;
    int v = (i < N_NODES) ? cnt[i] : 0;
    int s = iscan_block(v, threadIdx.x);
    if (i < N_NODES) rowptr[i] = s - v;
    if (threadIdx.x == 255) bsum[blockIdx.x] = s;
}

__global__ void k_scan_b(int* __restrict__ bsum, int nb) {
    int i = threadIdx.x;
    int v = (i < nb) ? bsum[i] : 0;
    int s = iscan_block(v, i);
    if (i < nb) bsum[i] = s - v;
}

__global__ void k_scan_c(int* __restrict__ rowptr, const int* __restrict__ bsum,
                         int* __restrict__ cursor) {
    int i = blockIdx.x * 256 + threadIdx.x;
    if (i < N_NODES) {
        int r = rowptr[i] + bsum[blockIdx.x];
        rowptr[i] = r;
        cursor[i] = r;
    }
    if (i == 0) rowptr[N_NODES] = N_EDGES;
}

__global__ void k_fill(const int* __restrict__ coli, const int* __restrict__ rowi,
                       int* __restrict__ cursor, int* __restrict__ elist,
                       int* __restrict__ rowg) {
    int e = blockIdx.x * blockDim.x + threadIdx.x;
    if (e < N_EDGES) {
        int p = atomicAdd(&cursor[coli[e]], 1);
        elist[p] = e;
        rowg[p] = rowi[e];
    }
}

// CSR position -> destination node (binary search over rowptr)
__global__ void k_posnode(const int* __restrict__ rowptr, int* __restrict__ posnode) {
    int p = blockIdx.x * blockDim.x + threadIdx.x;
    if (p >= N_EDGES) return;
    int lo = 0, hi = N_NODES;
    while (hi - lo > 1) {
        int mid = (lo + hi) >> 1;
        if (rowptr[mid] <= p) lo = mid; else hi = mid;
    }
    posnode[p] = lo;
}

// ---------------- xw1 = x @ W1a + b1 (f32 out, per node) ----------------
__global__ __launch_bounds__(256) void k_xw1(
    const ushort_t* __restrict__ xb, const ushort_t* __restrict__ w1at,
    const float* __restrict__ b1, float* __restrict__ xw1)
{
    __shared__ __align__(16) ushort_t As[64 * 64];
    __shared__ __align__(16) ushort_t Bs[256 * 64];
    const int tid = threadIdx.x;
    const int wave = tid >> 6, lane = tid & 63;
    const int lr = lane & 15, lh = lane >> 4;
    const int n0 = blockIdx.x * 64;

    const int sm = tid >> 2;
    const int sc = (tid & 3) << 4;
    int ns = n0 + sm; if (ns >= N_NODES) ns = N_NODES - 1;
    const ushort_t* xrow = xb + (size_t)ns * D;
    const ushort_t* wrow = w1at + (size_t)tid * D;
    const int swA = (sm & 7) << 3;
    const int swB = (tid & 7) << 3;

    f32x4 acc[4][4];
    #pragma unroll
    for (int i = 0; i < 4; ++i)
        #pragma unroll
        for (int j = 0; j < 4; ++j)
            acc[i][j] = (f32x4){0.f, 0.f, 0.f, 0.f};

    for (int kk = 0; kk < 4; ++kk) {
        const int k0 = kk << 6;
        const uint4* sx = (const uint4*)(xrow + k0 + sc);
        uint4 av0 = sx[0], av1 = sx[1];
        const uint4* wsv = (const uint4*)(wrow + k0);
        uint4 w0 = wsv[0], w1 = wsv[1], w2 = wsv[2], w3 = wsv[3];
        uint4 w4 = wsv[4], w5 = wsv[5], w6 = wsv[6], w7 = wsv[7];

        __syncthreads();
        *(uint4*)&As[sm * 64 + ( sc      ^ swA)] = av0;
        *(uint4*)&As[sm * 64 + ((sc + 8) ^ swA)] = av1;
        {
            const int base = tid * 64;
            *(uint4*)&Bs[base + ( 0 ^ swB)] = w0;
            *(uint4*)&Bs[base + ( 8 ^ swB)] = w1;
            *(uint4*)&Bs[base + (16 ^ swB)] = w2;
            *(uint4*)&Bs[base + (24 ^ swB)] = w3;
            *(uint4*)&Bs[base + (32 ^ swB)] = w4;
            *(uint4*)&Bs[base + (40 ^ swB)] = w5;
            *(uint4*)&Bs[base + (48 ^ swB)] = w6;
            *(uint4*)&Bs[base + (56 ^ swB)] = w7;
        }
        __syncthreads();

        #pragma unroll
        for (int kh = 0; kh < 2; ++kh) {
            const int kb = kh * 32 + lh * 8;
            bf16x8 af[4], bfr[4];
            #pragma unroll
            for (int i = 0; i < 4; ++i) {
                int m = i * 16 + lr;
                af[i] = *(const bf16x8*)&As[m * 64 + (kb ^ ((m & 7) << 3))];
            }
            #pragma unroll
            for (int j = 0; j < 4; ++j) {
                int n = wave * 64 + j * 16 + lr;
                bfr[j] = *(const bf16x8*)&Bs[n * 64 + (kb ^ ((n & 7) << 3))];
            }
            #pragma unroll
            for (int i = 0; i < 4; ++i)
                #pragma unroll
                for (int j = 0; j < 4; ++j)
                    acc[i][j] = __builtin_amdgcn_mfma_f32_16x16x32_bf16(af[i], bfr[j], acc[i][j], 0, 0, 0);
        }
    }

    float bv[4];
    #pragma unroll
    for (int j = 0; j < 4; ++j) bv[j] = b1[wave * 64 + j * 16 + lr];
    #pragma unroll
    for (int i = 0; i < 4; ++i) {
        #pragma unroll
        for (int r = 0; r < 4; ++r) {
            int m = i * 16 + lh * 4 + r;
            int node = n0 + m;
            if (node < N_NODES) {
                float* orow = xw1 + (size_t)node * D;
                #pragma unroll
                for (int j = 0; j < 4; ++j)
                    orow[wave * 64 + j * 16 + lr] = acc[i][j][r] + bv[j];
            }
        }
    }
}

// ---------------- edge GEMM (K=256) + in-register segmented aggregation ----------------
// processes CSR positions [p0, p0+64): e = elist[p]
// h[p] = relu( xw1[rowg[p]] + ea[e] @ W1b ); agg[node] += per-segment column sums
__global__ __launch_bounds__(256) void k_edge_csr(
    const float* __restrict__ ea, const ushort_t* __restrict__ w1bt,
    const float* __restrict__ xw1, const int* __restrict__ elist,
    const int* __restrict__ rowg, const int* __restrict__ posnode,
    const int* __restrict__ rowptr, float* __restrict__ agg)
{
    __shared__ __align__(16) ushort_t As[64 * 64];     // ea tile (bf16)
    __shared__ __align__(16) ushort_t Bs[256 * 64];    // W1b tile
    __shared__ int snd[64];                            // dest node per tile row
    __shared__ int ssr[64];                            // src node per tile row
    const int tid = threadIdx.x;
    const int wave = tid >> 6, lane = tid & 63;
    const int lr = lane & 15, lh = lane >> 4;
    const int p0 = blockIdx.x * 64;

    // row metadata (independent of GEMM; visible after first barrier)
    if (tid < 64) {
        int p = p0 + tid;
        int pc = min(p, N_EDGES - 1);
        snd[tid] = (p < N_EDGES) ? posnode[pc] : -1;
        ssr[tid] = rowg[pc];
    }

    const int sm = tid >> 2;
    const int sc = (tid & 3) << 4;
    int ps = p0 + sm; if (ps >= N_EDGES) ps = N_EDGES - 1;
    const int es = elist[ps];
    const float* earow = ea + (size_t)es * D;
    const ushort_t* wrow = w1bt + (size_t)tid * D;
    const int swA = (sm & 7) << 3;
    const int swB = (tid & 7) << 3;

    f32x4 acc[4][4];
    #pragma unroll
    for (int i = 0; i < 4; ++i)
        #pragma unroll
        for (int j = 0; j < 4; ++j)
            acc[i][j] = (f32x4){0.f, 0.f, 0.f, 0.f};

    #pragma unroll 1
    for (int kk = 0; kk < 4; ++kk) {
        const int k0 = kk << 6;
        const float4* s = (const float4*)(earow + k0 + sc);
        float4 f0 = s[0], f1 = s[1], f2 = s[2], f3 = s[3];
        uint4 av0, av1;
        av0.x = pk2(f0.x, f0.y); av0.y = pk2(f0.z, f0.w);
        av0.z = pk2(f1.x, f1.y); av0.w = pk2(f1.z, f1.w);
        av1.x = pk2(f2.x, f2.y); av1.y = pk2(f2.z, f2.w);
        av1.z = pk2(f3.x, f3.y); av1.w = pk2(f3.z, f3.w);
        const uint4* wsv = (const uint4*)(wrow + k0);
        uint4 w0 = wsv[0], w1 = wsv[1], w2 = wsv[2], w3 = wsv[3];
        uint4 w4 = wsv[4], w5 = wsv[5], w6 = wsv[6], w7 = wsv[7];

        __syncthreads();
        *(uint4*)&As[sm * 64 + ( sc      ^ swA)] = av0;
        *(uint4*)&As[sm * 64 + ((sc + 8) ^ swA)] = av1;
        {
            const int base = tid * 64;
            *(uint4*)&Bs[base + ( 0 ^ swB)] = w0;
            *(uint4*)&Bs[base + ( 8 ^ swB)] = w1;
            *(uint4*)&Bs[base + (16 ^ swB)] = w2;
            *(uint4*)&Bs[base + (24 ^ swB)] = w3;
            *(uint4*)&Bs[base + (32 ^ swB)] = w4;
            *(uint4*)&Bs[base + (40 ^ swB)] = w5;
            *(uint4*)&Bs[base + (48 ^ swB)] = w6;
            *(uint4*)&Bs[base + (56 ^ swB)] = w7;
        }
        __syncthreads();

        #pragma unroll
        for (int kh = 0; kh < 2; ++kh) {
            const int kb = kh * 32 + lh * 8;
            bf16x8 af[4], bfr[4];
            #pragma unroll
            for (int i = 0; i < 4; ++i) {
                int m = i * 16 + lr;
                af[i] = *(const bf16x8*)&As[m * 64 + (kb ^ ((m & 7) << 3))];
            }
            #pragma unroll
            for (int j = 0; j < 4; ++j) {
                int n = wave * 64 + j * 16 + lr;
                bfr[j] = *(const bf16x8*)&Bs[n * 64 + (kb ^ ((n & 7) << 3))];
            }
            #pragma unroll
            for (int i = 0; i < 4; ++i)
                #pragma unroll
                for (int j = 0; j < 4; ++j)
                    acc[i][j] = __builtin_amdgcn_mfma_f32_16x16x32_bf16(af[i], bfr[j], acc[i][j], 0, 0, 0);
        }
    }

    // ---- epilogue 1: add gathered xw1[src], relu, keep in registers ----
    #pragma unroll
    for (int i = 0; i < 4; ++i) {
        #pragma unroll
        for (int r = 0; r < 4; ++r) {
            const int m = i * 16 + lh * 4 + r;
            const bool ok = (p0 + m < N_EDGES);
            const int srow = ssr[m];
            const float* xr = xw1 + (size_t)srow * D + wave * 64 + lr;
            #pragma unroll
            for (int j = 0; j < 4; ++j) {
                float v = acc[i][j][r] + xr[j * 16];
                v = v > 0.f ? v : 0.f;
                acc[i][j][r] = ok ? v : 0.f;
            }
        }
    }

    // ---- epilogue 2: block-uniform segment loop, in-register reduce ----
    int a = 0;
    while (a < 64) {
        const int node = snd[a];
        int b = a + 1;
        while (b < 64 && snd[b] == node) ++b;
        if (node >= 0) {
            float s0 = 0.f, s1 = 0.f, s2 = 0.f, s3 = 0.f;
            #pragma unroll
            for (int i = 0; i < 4; ++i) {
                if (b <= i * 16 || a >= (i + 1) * 16) continue;  // uniform skip
                #pragma unroll
                for (int r = 0; r < 4; ++r) {
                    const int m = i * 16 + lh * 4 + r;
                    const bool in = (m >= a) && (m < b);
                    s0 += in ? acc[i][0][r] : 0.f;
                    s1 += in ? acc[i][1][r] : 0.f;
                    s2 += in ? acc[i][2][r] : 0.f;
                    s3 += in ? acc[i][3][r] : 0.f;
                }
            }
            // fold the 4 lh groups (lanes differ in bits 4,5)
            s0 += __shfl_xor(s0, 16, 64); s0 += __shfl_xor(s0, 32, 64);
            s1 += __shfl_xor(s1, 16, 64); s1 += __shfl_xor(s1, 32, 64);
            s2 += __shfl_xor(s2, 16, 64); s2 += __shfl_xor(s2, 32, 64);
            s3 += __shfl_xor(s3, 16, 64); s3 += __shfl_xor(s3, 32, 64);
            if (lh == 0) {
                const bool interior = (rowptr[node] >= p0) && (rowptr[node + 1] <= p0 + 64);
                float* dst = agg + (size_t)node * D + wave * 64 + lr;
                if (interior) {
                    dst[0]  = s0; dst[16] = s1; dst[32] = s2; dst[48] = s3;
                } else {
                    atomicAdd(&dst[0],  s0); atomicAdd(&dst[16], s1);
                    atomicAdd(&dst[32], s2); atomicAdd(&dst[48], s3);
                }
            }
        }
        a = b;
    }
}

// ---------------- node GEMM ----------------
// out[i][n] = relu( concat(x[i], agg[i]/max(cnt,1)) @ W2 + b2 )
__global__ __launch_bounds__(256) void k_node(
    const ushort_t* __restrict__ xb, const float* __restrict__ agg,
    const int* __restrict__ cnti,
    const ushort_t* __restrict__ w2t, const float* __restrict__ b2,
    float* __restrict__ out)
{
    __shared__ __align__(16) ushort_t As[64 * 64];
    __shared__ __align__(16) ushort_t Bs[256 * 64];
    const int tid = threadIdx.x;
    const int wave = tid >> 6, lane = tid & 63;
    const int lr = lane & 15, lh = lane >> 4;
    const int n0 = blockIdx.x * 64;

    const int sm = tid >> 2;
    const int sc = (tid & 3) << 4;
    int ns = n0 + sm; if (ns >= N_NODES) ns = N_NODES - 1;
    const ushort_t* xrow = xb + (size_t)ns * D;
    const float*    arow = agg + (size_t)ns * D;
    const float     ic   = 1.0f / fmaxf((float)cnti[ns], 1.0f);
    const ushort_t* wrow = w2t + (size_t)tid * TWO_D;
    const int swA = (sm & 7) << 3;
    const int swB = (tid & 7) << 3;

    f32x4 acc[4][4];
    #pragma unroll
    for (int i = 0; i < 4; ++i)
        #pragma unroll
        for (int j = 0; j < 4; ++j)
            acc[i][j] = (f32x4){0.f, 0.f, 0.f, 0.f};

    for (int kk = 0; kk < 8; ++kk) {
        const int k0 = kk << 6;
        uint4 av0, av1;
        if (kk < 4) {
            const uint4* s = (const uint4*)(xrow + k0 + sc);
            av0 = s[0]; av1 = s[1];
        } else {
            const float4* s = (const float4*)(arow + (k0 - D) + sc);
            float4 f0 = s[0], f1 = s[1], f2 = s[2], f3 = s[3];
            f0.x *= ic; f0.y *= ic; f0.z *= ic; f0.w *= ic;
            f1.x *= ic; f1.y *= ic; f1.z *= ic; f1.w *= ic;
            f2.x *= ic; f2.y *= ic; f2.z *= ic; f2.w *= ic;
            f3.x *= ic; f3.y *= ic; f3.z *= ic; f3.w *= ic;
            av0.x = pk2(f0.x, f0.y); av0.y = pk2(f0.z, f0.w);
            av0.z = pk2(f1.x, f1.y); av0.w = pk2(f1.z, f1.w);
            av1.x = pk2(f2.x, f2.y); av1.y = pk2(f2.z, f2.w);
            av1.z = pk2(f3.x, f3.y); av1.w = pk2(f3.z, f3.w);
        }
        const uint4* wsv = (const uint4*)(wrow + k0);
        uint4 w0 = wsv[0], w1 = wsv[1], w2 = wsv[2], w3 = wsv[3];
        uint4 w4 = wsv[4], w5 = wsv[5], w6 = wsv[6], w7 = wsv[7];

        __syncthreads();
        *(uint4*)&As[sm * 64 + ( sc      ^ swA)] = av0;
        *(uint4*)&As[sm * 64 + ((sc + 8) ^ swA)] = av1;
        {
            const int base = tid * 64;
            *(uint4*)&Bs[base + ( 0 ^ swB)] = w0;
            *(uint4*)&Bs[base + ( 8 ^ swB)] = w1;
            *(uint4*)&Bs[base + (16 ^ swB)] = w2;
            *(uint4*)&Bs[base + (24 ^ swB)] = w3;
            *(uint4*)&Bs[base + (32 ^ swB)] = w4;
            *(uint4*)&Bs[base + (40 ^ swB)] = w5;
            *(uint4*)&Bs[base + (48 ^ swB)] = w6;
            *(uint4*)&Bs[base + (56 ^ swB)] = w7;
        }
        __syncthreads();

        #pragma unroll
        for (int kh = 0; kh < 2; ++kh) {
            const int kb = kh * 32 + lh * 8;
            bf16x8 af[4], bfr[4];
            #pragma unroll
            for (int i = 0; i < 4; ++i) {
                int m = i * 16 + lr;
                af[i] = *(const bf16x8*)&As[m * 64 + (kb ^ ((m & 7) << 3))];
            }
            #pragma unroll
            for (int j = 0; j < 4; ++j) {
                int n = wave * 64 + j * 16 + lr;
                bfr[j] = *(const bf16x8*)&Bs[n * 64 + (kb ^ ((n & 7) << 3))];
            }
            #pragma unroll
            for (int i = 0; i < 4; ++i)
                #pragma unroll
                for (int j = 0; j < 4; ++j)
                    acc[i][j] = __builtin_amdgcn_mfma_f32_16x16x32_bf16(af[i], bfr[j], acc[i][j], 0, 0, 0);
        }
    }

    float bv[4];
    #pragma unroll
    for (int j = 0; j < 4; ++j) bv[j] = b2[wave * 64 + j * 16 + lr];
    #pragma unroll
    for (int i = 0; i < 4; ++i) {
        #pragma unroll
        for (int r = 0; r < 4; ++r) {
            int m = i * 16 + lh * 4 + r;
            int node = n0 + m;
            if (node < N_NODES) {
                float* orow = out + (size_t)node * D;
                #pragma unroll
                for (int j = 0; j < 4; ++j) {
                    float v = acc[i][j][r] + bv[j];
                    orow[wave * 64 + j * 16 + lr] = v > 0.f ? v : 0.f;
                }
            }
        }
    }
}

// ---------------- launch ----------------

extern "C" void kernel_launch(void* const* d_in, const int* in_sizes, int n_in,
                              void* d_out, int out_size, void* d_ws, size_t ws_size,
                              hipStream_t stream)
{
    const float* x  = (const float*)d_in[0];
    const int*   ei = (const int*)d_in[1];      // [2*E] int32: rows then cols
    const float* ea = (const float*)d_in[2];
    const float* W1 = (const float*)d_in[5];
    const float* b1 = (const float*)d_in[6];
    const float* W2 = (const float*)d_in[7];
    const float* b2 = (const float*)d_in[8];
    float* out = (float*)d_out;

    const int* rowi = ei;
    const int* coli = ei + N_EDGES;
    char* ws = (char*)d_ws;

    size_t off = 0;
    auto take = [&](size_t bytes) {
        char* p = ws + off;
        off = (off + bytes + 255) & ~(size_t)255;
        return p;
    };

    ushort_t* xb      = (ushort_t*)take((size_t)N_NODES * D * 2);
    ushort_t* w1at    = (ushort_t*)take((size_t)D * D * 2);
    ushort_t* w1bt    = (ushort_t*)take((size_t)D * D * 2);
    ushort_t* w2t     = (ushort_t*)take((size_t)D * TWO_D * 2);
    float*    xw1     = (float*)take((size_t)N_NODES * D * 4);
    float*    agg     = (float*)take((size_t)N_NODES * D * 4);
    int*      cnti    = (int*)take(50016 * 4);
    int*      rowptr  = (int*)take(50016 * 4);
    int*      cursor  = (int*)take(50016 * 4);
    int*      bsum    = (int*)take(256 * 4);
    int*      elist   = (int*)take((size_t)N_EDGES * 4);
    int*      rowg    = (int*)take((size_t)N_EDGES * 4);
    int*      posnode = (int*)take((size_t)N_EDGES * 4);

    const int NB = (N_NODES + 255) / 256;          // 196
    const int EB = (N_EDGES + 255) / 256;          // 1954
    const int NGB = (N_NODES + 63) / 64;           // 782
    const int EGB = (N_EDGES + 63) / 64;           // 7813

    k_cvt_x<<<(N_NODES * D / 8 + 255) / 256, 256, 0, stream>>>(x, xb, N_NODES * D / 8);
    k_wt   <<<D, 256, 0, stream>>>(W1, w1at, D);
    k_wt   <<<D, 256, 0, stream>>>(W1 + (size_t)D * D, w1bt, D);
    k_wt   <<<D, 256, 0, stream>>>(W2, w2t, TWO_D);

    k_zero   <<<49, 256, 0, stream>>>((float*)cnti, 50016 / 4);
    k_count_i<<<EB, 256, 0, stream>>>(coli, cnti);
    k_scan_a <<<NB, 256, 0, stream>>>(cnti, rowptr, bsum);
    k_scan_b <<<1, 256, 0, stream>>>(bsum, NB);
    k_scan_c <<<NB, 256, 0, stream>>>(rowptr, bsum, cursor);
    k_fill   <<<EB, 256, 0, stream>>>(coli, rowi, cursor, elist, rowg);
    k_posnode<<<EB, 256, 0, stream>>>(rowptr, posnode);

    k_xw1    <<<NGB, 256, 0, stream>>>(xb, w1at, b1, xw1);
    k_zero   <<<(N_NODES * D / 4 + 255) / 256, 256, 0, stream>>>(agg, N_NODES * D / 4);
    k_edge_csr<<<EGB, 256, 0, stream>>>(ea, w1bt, xw1, elist, rowg, posnode, rowptr, agg);
    k_node   <<<NGB, 256, 0, stream>>>(xb, agg, cnti, w2t, b2, out);
}

// Round 6
// 541.092 us; speedup vs baseline: 1.4701x; 1.0100x over previous
//
#include <hip/hip_runtime.h>

#define N_NODES 50000
#define N_EDGES 500000
#define D 256
#define TWO_D 512

typedef __attribute__((ext_vector_type(8))) __bf16 bf16x8;
typedef __attribute__((ext_vector_type(4))) float f32x4;
typedef unsigned short ushort_t;

__device__ __forceinline__ unsigned short f2bf(float f) {
    unsigned int u = __builtin_bit_cast(unsigned int, f);
    u += 0x7FFFu + ((u >> 16) & 1u);   // round-to-nearest-even
    return (unsigned short)(u >> 16);
}
__device__ __forceinline__ unsigned int pk2(float lo, float hi) {
    return (unsigned int)f2bf(lo) | ((unsigned int)f2bf(hi) << 16);
}

// ---------------- prep kernels ----------------

__global__ void k_zero(float* __restrict__ p, int n4) {
    int i = blockIdx.x * blockDim.x + threadIdx.x;
    if (i < n4) ((float4*)p)[i] = make_float4(0.f, 0.f, 0.f, 0.f);
}

__global__ void k_cvt_x(const float* __restrict__ x, ushort_t* __restrict__ xb, int n8) {
    int i = blockIdx.x * blockDim.x + threadIdx.x;
    if (i < n8) {
        const float4* s = (const float4*)(x + (size_t)i * 8);
        float4 a = s[0], b = s[1];
        uint4 o;
        o.x = pk2(a.x, a.y); o.y = pk2(a.z, a.w);
        o.z = pk2(b.x, b.y); o.w = pk2(b.z, b.w);
        *(uint4*)(xb + (size_t)i * 8) = o;
    }
}

// W slice [KW rows of D cols] f32 -> Wt [D][KW] bf16 (transposed)
__global__ void k_wt(const float* __restrict__ w, ushort_t* __restrict__ wt, int KW) {
    int n = blockIdx.x;
    for (int k = threadIdx.x; k < KW; k += blockDim.x)
        wt[(size_t)n * KW + k] = f2bf(w[(size_t)k * D + n]);
}

__global__ void k_count_i(const int* __restrict__ coli, int* __restrict__ cnt) {
    int e = blockIdx.x * blockDim.x + threadIdx.x;
    if (e < N_EDGES) atomicAdd(&cnt[coli[e]], 1);
}

// ---------------- CSR build ----------------

__device__ __forceinline__ int iscan_block(int v, int tid) {
    int lane = tid & 63, wv = tid >> 6;
    int s = v;
    #pragma unroll
    for (int off = 1; off < 64; off <<= 1) {
        int t = __shfl_up(s, off, 64);
        if (lane >= off) s += t;
    }
    __shared__ int wsum[4];
    if (lane == 63) wsum[wv] = s;
    __syncthreads();
    #pragma unroll
    for (int w = 0; w < 3; ++w)
        if (wv > w) s += wsum[w];
    return s;
}

__global__ void k_scan_a(const int* __restrict__ cnt, int* __restrict__ rowptr,
                         int* __restrict__ bsum) {
    int i = blockIdx.x * 256 + threadIdx.x;
    int v = (i < N_NODES) ? cnt[i] : 0;
    int s = iscan_block(v, threadIdx.x);
    if (i < N_NODES) rowptr[i] = s - v;
    if (threadIdx.x == 255) bsum[blockIdx.x] = s;
}

__global__ void k_scan_b(int* __restrict__ bsum, int nb) {
    int i = threadIdx.x;
    int v = (i < nb) ? bsum[i] : 0;
    int s = iscan_block(v, i);
    if (i < nb) bsum[i] = s - v;
}

__global__ void k_scan_c(int* __restrict__ rowptr, const int* __restrict__ bsum,
                         int* __restrict__ cursor) {
    int i = blockIdx.x * 256 + threadIdx.x;
    if (i < N_NODES) {
        int r = rowptr[i] + bsum[blockIdx.x];
        rowptr[i] = r;
        cursor[i] = r;
    }
    if (i == 0) rowptr[N_NODES] = N_EDGES;
}

__global__ void k_fill(const int* __restrict__ coli, const int* __restrict__ rowi,
                       int* __restrict__ cursor, int* __restrict__ elist,
                       int* __restrict__ rowg) {
    int e = blockIdx.x * blockDim.x + threadIdx.x;
    if (e < N_EDGES) {
        int p = atomicAdd(&cursor[coli[e]], 1);
        elist[p] = e;
        rowg[p] = rowi[e];
    }
}

// CSR position -> destination node (binary search over rowptr)
__global__ void k_posnode(const int* __restrict__ rowptr, int* __restrict__ posnode) {
    int p = blockIdx.x * blockDim.x + threadIdx.x;
    if (p >= N_EDGES) return;
    int lo = 0, hi = N_NODES;
    while (hi - lo > 1) {
        int mid = (lo + hi) >> 1;
        if (rowptr[mid] <= p) lo = mid; else hi = mid;
    }
    posnode[p] = lo;
}

// ---------------- xw1 = x @ W1a + b1 (f32 out, per node) ----------------
__global__ __launch_bounds__(256) void k_xw1(
    const ushort_t* __restrict__ xb, const ushort_t* __restrict__ w1at,
    const float* __restrict__ b1, float* __restrict__ xw1)
{
    __shared__ __align__(16) ushort_t As[64 * 64];
    __shared__ __align__(16) ushort_t Bs[256 * 64];
    const int tid = threadIdx.x;
    const int wave = tid >> 6, lane = tid & 63;
    const int lr = lane & 15, lh = lane >> 4;
    const int n0 = blockIdx.x * 64;

    const int sm = tid >> 2;
    const int sc = (tid & 3) << 4;
    int ns = n0 + sm; if (ns >= N_NODES) ns = N_NODES - 1;
    const ushort_t* xrow = xb + (size_t)ns * D;
    const ushort_t* wrow = w1at + (size_t)tid * D;
    const int swA = (sm & 7) << 3;
    const int swB = (tid & 7) << 3;

    f32x4 acc[4][4];
    #pragma unroll
    for (int i = 0; i < 4; ++i)
        #pragma unroll
        for (int j = 0; j < 4; ++j)
            acc[i][j] = (f32x4){0.f, 0.f, 0.f, 0.f};

    for (int kk = 0; kk < 4; ++kk) {
        const int k0 = kk << 6;
        const uint4* sx = (const uint4*)(xrow + k0 + sc);
        uint4 av0 = sx[0], av1 = sx[1];
        const uint4* wsv = (const uint4*)(wrow + k0);
        uint4 w0 = wsv[0], w1 = wsv[1], w2 = wsv[2], w3 = wsv[3];
        uint4 w4 = wsv[4], w5 = wsv[5], w6 = wsv[6], w7 = wsv[7];

        __syncthreads();
        *(uint4*)&As[sm * 64 + ( sc      ^ swA)] = av0;
        *(uint4*)&As[sm * 64 + ((sc + 8) ^ swA)] = av1;
        {
            const int base = tid * 64;
            *(uint4*)&Bs[base + ( 0 ^ swB)] = w0;
            *(uint4*)&Bs[base + ( 8 ^ swB)] = w1;
            *(uint4*)&Bs[base + (16 ^ swB)] = w2;
            *(uint4*)&Bs[base + (24 ^ swB)] = w3;
            *(uint4*)&Bs[base + (32 ^ swB)] = w4;
            *(uint4*)&Bs[base + (40 ^ swB)] = w5;
            *(uint4*)&Bs[base + (48 ^ swB)] = w6;
            *(uint4*)&Bs[base + (56 ^ swB)] = w7;
        }
        __syncthreads();

        #pragma unroll
        for (int kh = 0; kh < 2; ++kh) {
            const int kb = kh * 32 + lh * 8;
            bf16x8 af[4], bfr[4];
            #pragma unroll
            for (int i = 0; i < 4; ++i) {
                int m = i * 16 + lr;
                af[i] = *(const bf16x8*)&As[m * 64 + (kb ^ ((m & 7) << 3))];
            }
            #pragma unroll
            for (int j = 0; j < 4; ++j) {
                int n = wave * 64 + j * 16 + lr;
                bfr[j] = *(const bf16x8*)&Bs[n * 64 + (kb ^ ((n & 7) << 3))];
            }
            #pragma unroll
            for (int i = 0; i < 4; ++i)
                #pragma unroll
                for (int j = 0; j < 4; ++j)
                    acc[i][j] = __builtin_amdgcn_mfma_f32_16x16x32_bf16(af[i], bfr[j], acc[i][j], 0, 0, 0);
        }
    }

    float bv[4];
    #pragma unroll
    for (int j = 0; j < 4; ++j) bv[j] = b1[wave * 64 + j * 16 + lr];
    #pragma unroll
    for (int i = 0; i < 4; ++i) {
        #pragma unroll
        for (int r = 0; r < 4; ++r) {
            int m = i * 16 + lh * 4 + r;
            int node = n0 + m;
            if (node < N_NODES) {
                float* orow = xw1 + (size_t)node * D;
                #pragma unroll
                for (int j = 0; j < 4; ++j)
                    orow[wave * 64 + j * 16 + lr] = acc[i][j][r] + bv[j];
            }
        }
    }
}

// ---------------- edge GEMM (K=256) + in-register segmented aggregation ----------------
// processes CSR positions [p0, p0+64): e = elist[p]
// h[p] = relu( xw1[rowg[p]] + ea[e] @ W1b ); agg[node] += per-segment column sums
// Round-4 proven body; ONLY change: xw1 gathers hoisted before the GEMM so their
// latency hides under the K-loop (they were a serial tail stall in round 4).
__global__ __launch_bounds__(256, 2) void k_edge_csr(
    const float* __restrict__ ea, const ushort_t* __restrict__ w1bt,
    const float* __restrict__ xw1, const int* __restrict__ elist,
    const int* __restrict__ rowg, const int* __restrict__ posnode,
    const int* __restrict__ rowptr, float* __restrict__ agg)
{
    __shared__ __align__(16) ushort_t As[64 * 64];     // ea tile (bf16)
    __shared__ __align__(16) ushort_t Bs[256 * 64];    // W1b tile
    __shared__ int snd[64];                            // dest node per tile row
    const int tid = threadIdx.x;
    const int wave = tid >> 6, lane = tid & 63;
    const int lr = lane & 15, lh = lane >> 4;
    const int p0 = blockIdx.x * 64;

    // row metadata (visible after first barrier)
    if (tid < 64) {
        int p = p0 + tid;
        int pc = min(p, N_EDGES - 1);
        snd[tid] = (p < N_EDGES) ? posnode[pc] : -1;
    }

    const int sm = tid >> 2;
    const int sc = (tid & 3) << 4;
    int ps = p0 + sm; if (ps >= N_EDGES) ps = N_EDGES - 1;
    const int es = elist[ps];
    const float* earow = ea + (size_t)es * D;
    const ushort_t* wrow = w1bt + (size_t)tid * D;
    const int swA = (sm & 7) << 3;
    const int swB = (tid & 7) << 3;

    // ---- hoisted epilogue gathers: complete under the GEMM ----
    float xwv[4][4][4];   // [i][r][j]
    #pragma unroll
    for (int i = 0; i < 4; ++i)
        #pragma unroll
        for (int r = 0; r < 4; ++r) {
            const int srw = rowg[min(p0 + i * 16 + lh * 4 + r, N_EDGES - 1)];
            const float* xr = xw1 + (size_t)srw * D + wave * 64 + lr;
            #pragma unroll
            for (int j = 0; j < 4; ++j)
                xwv[i][r][j] = xr[j * 16];
        }

    f32x4 acc[4][4];
    #pragma unroll
    for (int i = 0; i < 4; ++i)
        #pragma unroll
        for (int j = 0; j < 4; ++j)
            acc[i][j] = (f32x4){0.f, 0.f, 0.f, 0.f};

    #pragma unroll 1
    for (int kk = 0; kk < 4; ++kk) {
        const int k0 = kk << 6;
        const float4* s = (const float4*)(earow + k0 + sc);
        float4 f0 = s[0], f1 = s[1], f2 = s[2], f3 = s[3];
        uint4 av0, av1;
        av0.x = pk2(f0.x, f0.y); av0.y = pk2(f0.z, f0.w);
        av0.z = pk2(f1.x, f1.y); av0.w = pk2(f1.z, f1.w);
        av1.x = pk2(f2.x, f2.y); av1.y = pk2(f2.z, f2.w);
        av1.z = pk2(f3.x, f3.y); av1.w = pk2(f3.z, f3.w);
        const uint4* wsv = (const uint4*)(wrow + k0);
        uint4 w0 = wsv[0], w1 = wsv[1], w2 = wsv[2], w3 = wsv[3];
        uint4 w4 = wsv[4], w5 = wsv[5], w6 = wsv[6], w7 = wsv[7];

        __syncthreads();
        *(uint4*)&As[sm * 64 + ( sc      ^ swA)] = av0;
        *(uint4*)&As[sm * 64 + ((sc + 8) ^ swA)] = av1;
        {
            const int base = tid * 64;
            *(uint4*)&Bs[base + ( 0 ^ swB)] = w0;
            *(uint4*)&Bs[base + ( 8 ^ swB)] = w1;
            *(uint4*)&Bs[base + (16 ^ swB)] = w2;
            *(uint4*)&Bs[base + (24 ^ swB)] = w3;
            *(uint4*)&Bs[base + (32 ^ swB)] = w4;
            *(uint4*)&Bs[base + (40 ^ swB)] = w5;
            *(uint4*)&Bs[base + (48 ^ swB)] = w6;
            *(uint4*)&Bs[base + (56 ^ swB)] = w7;
        }
        __syncthreads();

        #pragma unroll
        for (int kh = 0; kh < 2; ++kh) {
            const int kb = kh * 32 + lh * 8;
            bf16x8 af[4], bfr[4];
            #pragma unroll
            for (int i = 0; i < 4; ++i) {
                int m = i * 16 + lr;
                af[i] = *(const bf16x8*)&As[m * 64 + (kb ^ ((m & 7) << 3))];
            }
            #pragma unroll
            for (int j = 0; j < 4; ++j) {
                int n = wave * 64 + j * 16 + lr;
                bfr[j] = *(const bf16x8*)&Bs[n * 64 + (kb ^ ((n & 7) << 3))];
            }
            #pragma unroll
            for (int i = 0; i < 4; ++i)
                #pragma unroll
                for (int j = 0; j < 4; ++j)
                    acc[i][j] = __builtin_amdgcn_mfma_f32_16x16x32_bf16(af[i], bfr[j], acc[i][j], 0, 0, 0);
        }
    }

    // ---- epilogue 1: add prefetched xw1[src], relu, keep in registers ----
    #pragma unroll
    for (int i = 0; i < 4; ++i) {
        #pragma unroll
        for (int r = 0; r < 4; ++r) {
            const int m = i * 16 + lh * 4 + r;
            const bool ok = (p0 + m < N_EDGES);
            #pragma unroll
            for (int j = 0; j < 4; ++j) {
                float v = acc[i][j][r] + xwv[i][r][j];
                v = v > 0.f ? v : 0.f;
                acc[i][j][r] = ok ? v : 0.f;
            }
        }
    }

    // ---- epilogue 2: block-uniform segment loop, in-register reduce (round-4 proven) ----
    int a = 0;
    while (a < 64) {
        const int node = snd[a];
        int b = a + 1;
        while (b < 64 && snd[b] == node) ++b;
        if (node >= 0) {
            float s0 = 0.f, s1 = 0.f, s2 = 0.f, s3 = 0.f;
            #pragma unroll
            for (int i = 0; i < 4; ++i) {
                if (b <= i * 16 || a >= (i + 1) * 16) continue;  // uniform skip
                #pragma unroll
                for (int r = 0; r < 4; ++r) {
                    const int m = i * 16 + lh * 4 + r;
                    const bool in = (m >= a) && (m < b);
                    s0 += in ? acc[i][0][r] : 0.f;
                    s1 += in ? acc[i][1][r] : 0.f;
                    s2 += in ? acc[i][2][r] : 0.f;
                    s3 += in ? acc[i][3][r] : 0.f;
                }
            }
            // fold the 4 lh groups (lanes differ in bits 4,5)
            s0 += __shfl_xor(s0, 16, 64); s0 += __shfl_xor(s0, 32, 64);
            s1 += __shfl_xor(s1, 16, 64); s1 += __shfl_xor(s1, 32, 64);
            s2 += __shfl_xor(s2, 16, 64); s2 += __shfl_xor(s2, 32, 64);
            s3 += __shfl_xor(s3, 16, 64); s3 += __shfl_xor(s3, 32, 64);
            if (lh == 0) {
                const bool interior = (rowptr[node] >= p0) && (rowptr[node + 1] <= p0 + 64);
                float* dst = agg + (size_t)node * D + wave * 64 + lr;
                if (interior) {
                    dst[0]  = s0; dst[16] = s1; dst[32] = s2; dst[48] = s3;
                } else {
                    atomicAdd(&dst[0],  s0); atomicAdd(&dst[16], s1);
                    atomicAdd(&dst[32], s2); atomicAdd(&dst[48], s3);
                }
            }
        }
        a = b;
    }
}

// ---------------- node GEMM ----------------
// out[i][n] = relu( concat(x[i], agg[i]/max(cnt,1)) @ W2 + b2 )
__global__ __launch_bounds__(256) void k_node(
    const ushort_t* __restrict__ xb, const float* __restrict__ agg,
    const int* __restrict__ cnti,
    const ushort_t* __restrict__ w2t, const float* __restrict__ b2,
    float* __restrict__ out)
{
    __shared__ __align__(16) ushort_t As[64 * 64];
    __shared__ __align__(16) ushort_t Bs[256 * 64];
    const int tid = threadIdx.x;
    const int wave = tid >> 6, lane = tid & 63;
    const int lr = lane & 15, lh = lane >> 4;
    const int n0 = blockIdx.x * 64;

    const int sm = tid >> 2;
    const int sc = (tid & 3) << 4;
    int ns = n0 + sm; if (ns >= N_NODES) ns = N_NODES - 1;
    const ushort_t* xrow = xb + (size_t)ns * D;
    const float*    arow = agg + (size_t)ns * D;
    const float     ic   = 1.0f / fmaxf((float)cnti[ns], 1.0f);
    const ushort_t* wrow = w2t + (size_t)tid * TWO_D;
    const int swA = (sm & 7) << 3;
    const int swB = (tid & 7) << 3;

    f32x4 acc[4][4];
    #pragma unroll
    for (int i = 0; i < 4; ++i)
        #pragma unroll
        for (int j = 0; j < 4; ++j)
            acc[i][j] = (f32x4){0.f, 0.f, 0.f, 0.f};

    for (int kk = 0; kk < 8; ++kk) {
        const int k0 = kk << 6;
        uint4 av0, av1;
        if (kk < 4) {
            const uint4* s = (const uint4*)(xrow + k0 + sc);
            av0 = s[0]; av1 = s[1];
        } else {
            const float4* s = (const float4*)(arow + (k0 - D) + sc);
            float4 f0 = s[0], f1 = s[1], f2 = s[2], f3 = s[3];
            f0.x *= ic; f0.y *= ic; f0.z *= ic; f0.w *= ic;
            f1.x *= ic; f1.y *= ic; f1.z *= ic; f1.w *= ic;
            f2.x *= ic; f2.y *= ic; f2.z *= ic; f2.w *= ic;
            f3.x *= ic; f3.y *= ic; f3.z *= ic; f3.w *= ic;
            av0.x = pk2(f0.x, f0.y); av0.y = pk2(f0.z, f0.w);
            av0.z = pk2(f1.x, f1.y); av0.w = pk2(f1.z, f1.w);
            av1.x = pk2(f2.x, f2.y); av1.y = pk2(f2.z, f2.w);
            av1.z = pk2(f3.x, f3.y); av1.w = pk2(f3.z, f3.w);
        }
        const uint4* wsv = (const uint4*)(wrow + k0);
        uint4 w0 = wsv[0], w1 = wsv[1], w2 = wsv[2], w3 = wsv[3];
        uint4 w4 = wsv[4], w5 = wsv[5], w6 = wsv[6], w7 = wsv[7];

        __syncthreads();
        *(uint4*)&As[sm * 64 + ( sc      ^ swA)] = av0;
        *(uint4*)&As[sm * 64 + ((sc + 8) ^ swA)] = av1;
        {
            const int base = tid * 64;
            *(uint4*)&Bs[base + ( 0 ^ swB)] = w0;
            *(uint4*)&Bs[base + ( 8 ^ swB)] = w1;
            *(uint4*)&Bs[base + (16 ^ swB)] = w2;
            *(uint4*)&Bs[base + (24 ^ swB)] = w3;
            *(uint4*)&Bs[base + (32 ^ swB)] = w4;
            *(uint4*)&Bs[base + (40 ^ swB)] = w5;
            *(uint4*)&Bs[base + (48 ^ swB)] = w6;
            *(uint4*)&Bs[base + (56 ^ swB)] = w7;
        }
        __syncthreads();

        #pragma unroll
        for (int kh = 0; kh < 2; ++kh) {
            const int kb = kh * 32 + lh * 8;
            bf16x8 af[4], bfr[4];
            #pragma unroll
            for (int i = 0; i < 4; ++i) {
                int m = i * 16 + lr;
                af[i] = *(const bf16x8*)&As[m * 64 + (kb ^ ((m & 7) << 3))];
            }
            #pragma unroll
            for (int j = 0; j < 4; ++j) {
                int n = wave * 64 + j * 16 + lr;
                bfr[j] = *(const bf16x8*)&Bs[n * 64 + (kb ^ ((n & 7) << 3))];
            }
            #pragma unroll
            for (int i = 0; i < 4; ++i)
                #pragma unroll
                for (int j = 0; j < 4; ++j)
                    acc[i][j] = __builtin_amdgcn_mfma_f32_16x16x32_bf16(af[i], bfr[j], acc[i][j], 0, 0, 0);
        }
    }

    float bv[4];
    #pragma unroll
    for (int j = 0; j < 4; ++j) bv[j] = b2[wave * 64 + j * 16 + lr];
    #pragma unroll
    for (int i = 0; i < 4; ++i) {
        #pragma unroll
        for (int r = 0; r < 4; ++r) {
            int m = i * 16 + lh * 4 + r;
            int node = n0 + m;
            if (node < N_NODES) {
                float* orow = out + (size_t)node * D;
                #pragma unroll
                for (int j = 0; j < 4; ++j) {
                    float v = acc[i][j][r] + bv[j];
                    orow[wave * 64 + j * 16 + lr] = v > 0.f ? v : 0.f;
                }
            }
        }
    }
}

// ---------------- launch ----------------

extern "C" void kernel_launch(void* const* d_in, const int* in_sizes, int n_in,
                              void* d_out, int out_size, void* d_ws, size_t ws_size,
                              hipStream_t stream)
{
    const float* x  = (const float*)d_in[0];
    const int*   ei = (const int*)d_in[1];      // [2*E] int32: rows then cols
    const float* ea = (const float*)d_in[2];
    const float* W1 = (const float*)d_in[5];
    const float* b1 = (const float*)d_in[6];
    const float* W2 = (const float*)d_in[7];
    const float* b2 = (const float*)d_in[8];
    float* out = (float*)d_out;

    const int* rowi = ei;
    const int* coli = ei + N_EDGES;
    char* ws = (char*)d_ws;

    size_t off = 0;
    auto take = [&](size_t bytes) {
        char* p = ws + off;
        off = (off + bytes + 255) & ~(size_t)255;
        return p;
    };

    ushort_t* xb      = (ushort_t*)take((size_t)N_NODES * D * 2);
    ushort_t* w1at    = (ushort_t*)take((size_t)D * D * 2);
    ushort_t* w1bt    = (ushort_t*)take((size_t)D * D * 2);
    ushort_t* w2t     = (ushort_t*)take((size_t)D * TWO_D * 2);
    float*    xw1     = (float*)take((size_t)N_NODES * D * 4);
    float*    agg     = (float*)take((size_t)N_NODES * D * 4);
    int*      cnti    = (int*)take(50016 * 4);
    int*      rowptr  = (int*)take(50016 * 4);
    int*      cursor  = (int*)take(50016 * 4);
    int*      bsum    = (int*)take(256 * 4);
    int*      elist   = (int*)take((size_t)N_EDGES * 4);
    int*      rowg    = (int*)take((size_t)N_EDGES * 4);
    int*      posnode = (int*)take((size_t)N_EDGES * 4);

    const int NB = (N_NODES + 255) / 256;          // 196
    const int EB = (N_EDGES + 255) / 256;          // 1954
    const int NGB = (N_NODES + 63) / 64;           // 782
    const int EGB = (N_EDGES + 63) / 64;           // 7813

    k_cvt_x<<<(N_NODES * D / 8 + 255) / 256, 256, 0, stream>>>(x, xb, N_NODES * D / 8);
    k_wt   <<<D, 256, 0, stream>>>(W1, w1at, D);
    k_wt   <<<D, 256, 0, stream>>>(W1 + (size_t)D * D, w1bt, D);
    k_wt   <<<D, 256, 0, stream>>>(W2, w2t, TWO_D);

    k_zero   <<<49, 256, 0, stream>>>((float*)cnti, 50016 / 4);
    k_count_i<<<EB, 256, 0, stream>>>(coli, cnti);
    k_scan_a <<<NB, 256, 0, stream>>>(cnti, rowptr, bsum);
    k_scan_b <<<1, 256, 0, stream>>>(bsum, NB);
    k_scan_c <<<NB, 256, 0, stream>>>(rowptr, bsum, cursor);
    k_fill   <<<EB, 256, 0, stream>>>(coli, rowi, cursor, elist, rowg);
    k_posnode<<<EB, 256, 0, stream>>>(rowptr, posnode);

    k_xw1    <<<NGB, 256, 0, stream>>>(xb, w1at, b1, xw1);
    k_zero   <<<(N_NODES * D / 4 + 255) / 256, 256, 0, stream>>>(agg, N_NODES * D / 4);
    k_edge_csr<<<EGB, 256, 0, stream>>>(ea, w1bt, xw1, elist, rowg, posnode, rowptr, agg);
    k_node   <<<NGB, 256, 0, stream>>>(xb, agg, cnti, w2t, b2, out);
}

// Round 7
// 502.381 us; speedup vs baseline: 1.5834x; 1.0771x over previous
//
#include <hip/hip_runtime.h>

#define N_NODES 50000
#define N_EDGES 500000
#define D 256
#define TWO_D 512

typedef __attribute__((ext_vector_type(8))) __bf16 bf16x8;
typedef __attribute__((ext_vector_type(4))) float f32x4;
typedef unsigned short ushort_t;

__device__ __forceinline__ unsigned short f2bf(float f) {
    unsigned int u = __builtin_bit_cast(unsigned int, f);
    u += 0x7FFFu + ((u >> 16) & 1u);   // round-to-nearest-even
    return (unsigned short)(u >> 16);
}
__device__ __forceinline__ unsigned int pk2(float lo, float hi) {
    return (unsigned int)f2bf(lo) | ((unsigned int)f2bf(hi) << 16);
}

// ---------------- prep kernels ----------------

__global__ void k_zero(float* __restrict__ p, int n4) {
    int i = blockIdx.x * blockDim.x + threadIdx.x;
    if (i < n4) ((float4*)p)[i] = make_float4(0.f, 0.f, 0.f, 0.f);
}

__global__ void k_cvt_x(const float* __restrict__ x, ushort_t* __restrict__ xb, int n8) {
    int i = blockIdx.x * blockDim.x + threadIdx.x;
    if (i < n8) {
        const float4* s = (const float4*)(x + (size_t)i * 8);
        float4 a = s[0], b = s[1];
        uint4 o;
        o.x = pk2(a.x, a.y); o.y = pk2(a.z, a.w);
        o.z = pk2(b.x, b.y); o.w = pk2(b.z, b.w);
        *(uint4*)(xb + (size_t)i * 8) = o;
    }
}

// W slice [KW rows of D cols] f32 -> Wt [D][KW] bf16 (transposed)
__global__ void k_wt(const float* __restrict__ w, ushort_t* __restrict__ wt, int KW) {
    int n = blockIdx.x;
    for (int k = threadIdx.x; k < KW; k += blockDim.x)
        wt[(size_t)n * KW + k] = f2bf(w[(size_t)k * D + n]);
}

__global__ void k_count_i(const int* __restrict__ coli, int* __restrict__ cnt) {
    int e = blockIdx.x * blockDim.x + threadIdx.x;
    if (e < N_EDGES) atomicAdd(&cnt[coli[e]], 1);
}

// ---------------- CSR build ----------------

__device__ __forceinline__ int iscan_block(int v, int tid) {
    int lane = tid & 63, wv = tid >> 6;
    int s = v;
    #pragma unroll
    for (int off = 1; off < 64; off <<= 1) {
        int t = __shfl_up(s, off, 64);
        if (lane >= off) s += t;
    }
    __shared__ int wsum[4];
    if (lane == 63) wsum[wv] = s;
    __syncthreads();
    #pragma unroll
    for (int w = 0; w < 3; ++w)
        if (wv > w) s += wsum[w];
    return s;
}

__global__ void k_scan_a(const int* __restrict__ cnt, int* __restrict__ rowptr,
                         int* __restrict__ bsum) {
    int i = blockIdx.x * 256 + threadIdx.x;
    int v = (i < N_NODES) ? cnt[i] : 0;
    int s = iscan_block(v, threadIdx.x);
    if (i < N_NODES) rowptr[i] = s - v;
    if (threadIdx.x == 255) bsum[blockIdx.x] = s;
}

__global__ void k_scan_b(int* __restrict__ bsum, int nb) {
    int i = threadIdx.x;
    int v = (i < nb) ? bsum[i] : 0;
    int s = iscan_block(v, i);
    if (i < nb) bsum[i] = s - v;
}

__global__ void k_scan_c(int* __restrict__ rowptr, const int* __restrict__ bsum,
                         int* __restrict__ cursor) {
    int i = blockIdx.x * 256 + threadIdx.x;
    if (i < N_NODES) {
        int r = rowptr[i] + bsum[blockIdx.x];
        rowptr[i] = r;
        cursor[i] = r;
    }
    if (i == 0) rowptr[N_NODES] = N_EDGES;
}

__global__ void k_fill(const int* __restrict__ coli, const int* __restrict__ rowi,
                       int* __restrict__ cursor, int* __restrict__ elist,
                       int* __restrict__ rowg) {
    int e = blockIdx.x * blockDim.x + threadIdx.x;
    if (e < N_EDGES) {
        int p = atomicAdd(&cursor[coli[e]], 1);
        elist[p] = e;
        rowg[p] = rowi[e];
    }
}

// CSR position -> destination node (binary search over rowptr)
__global__ void k_posnode(const int* __restrict__ rowptr, int* __restrict__ posnode) {
    int p = blockIdx.x * blockDim.x + threadIdx.x;
    if (p >= N_EDGES) return;
    int lo = 0, hi = N_NODES;
    while (hi - lo > 1) {
        int mid = (lo + hi) >> 1;
        if (rowptr[mid] <= p) lo = mid; else hi = mid;
    }
    posnode[p] = lo;
}

// ---------------- xw1 = x @ W1a + b1 (f32 out, per node) ----------------
__global__ __launch_bounds__(256) void k_xw1(
    const ushort_t* __restrict__ xb, const ushort_t* __restrict__ w1at,
    const float* __restrict__ b1, float* __restrict__ xw1)
{
    __shared__ __align__(16) ushort_t As[64 * 64];
    __shared__ __align__(16) ushort_t Bs[256 * 64];
    const int tid = threadIdx.x;
    const int wave = tid >> 6, lane = tid & 63;
    const int lr = lane & 15, lh = lane >> 4;
    const int n0 = blockIdx.x * 64;

    const int sm = tid >> 2;
    const int sc = (tid & 3) << 4;
    int ns = n0 + sm; if (ns >= N_NODES) ns = N_NODES - 1;
    const ushort_t* xrow = xb + (size_t)ns * D;
    const ushort_t* wrow = w1at + (size_t)tid * D;
    const int swA = (sm & 7) << 3;
    const int swB = (tid & 7) << 3;

    f32x4 acc[4][4];
    #pragma unroll
    for (int i = 0; i < 4; ++i)
        #pragma unroll
        for (int j = 0; j < 4; ++j)
            acc[i][j] = (f32x4){0.f, 0.f, 0.f, 0.f};

    for (int kk = 0; kk < 4; ++kk) {
        const int k0 = kk << 6;
        const uint4* sx = (const uint4*)(xrow + k0 + sc);
        uint4 av0 = sx[0], av1 = sx[1];
        const uint4* wsv = (const uint4*)(wrow + k0);
        uint4 w0 = wsv[0], w1 = wsv[1], w2 = wsv[2], w3 = wsv[3];
        uint4 w4 = wsv[4], w5 = wsv[5], w6 = wsv[6], w7 = wsv[7];

        __syncthreads();
        *(uint4*)&As[sm * 64 + ( sc      ^ swA)] = av0;
        *(uint4*)&As[sm * 64 + ((sc + 8) ^ swA)] = av1;
        {
            const int base = tid * 64;
            *(uint4*)&Bs[base + ( 0 ^ swB)] = w0;
            *(uint4*)&Bs[base + ( 8 ^ swB)] = w1;
            *(uint4*)&Bs[base + (16 ^ swB)] = w2;
            *(uint4*)&Bs[base + (24 ^ swB)] = w3;
            *(uint4*)&Bs[base + (32 ^ swB)] = w4;
            *(uint4*)&Bs[base + (40 ^ swB)] = w5;
            *(uint4*)&Bs[base + (48 ^ swB)] = w6;
            *(uint4*)&Bs[base + (56 ^ swB)] = w7;
        }
        __syncthreads();

        #pragma unroll
        for (int kh = 0; kh < 2; ++kh) {
            const int kb = kh * 32 + lh * 8;
            bf16x8 af[4], bfr[4];
            #pragma unroll
            for (int i = 0; i < 4; ++i) {
                int m = i * 16 + lr;
                af[i] = *(const bf16x8*)&As[m * 64 + (kb ^ ((m & 7) << 3))];
            }
            #pragma unroll
            for (int j = 0; j < 4; ++j) {
                int n = wave * 64 + j * 16 + lr;
                bfr[j] = *(const bf16x8*)&Bs[n * 64 + (kb ^ ((n & 7) << 3))];
            }
            #pragma unroll
            for (int i = 0; i < 4; ++i)
                #pragma unroll
                for (int j = 0; j < 4; ++j)
                    acc[i][j] = __builtin_amdgcn_mfma_f32_16x16x32_bf16(af[i], bfr[j], acc[i][j], 0, 0, 0);
        }
    }

    float bv[4];
    #pragma unroll
    for (int j = 0; j < 4; ++j) bv[j] = b1[wave * 64 + j * 16 + lr];
    #pragma unroll
    for (int i = 0; i < 4; ++i) {
        #pragma unroll
        for (int r = 0; r < 4; ++r) {
            int m = i * 16 + lh * 4 + r;
            int node = n0 + m;
            if (node < N_NODES) {
                float* orow = xw1 + (size_t)node * D;
                #pragma unroll
                for (int j = 0; j < 4; ++j)
                    orow[wave * 64 + j * 16 + lr] = acc[i][j][r] + bv[j];
            }
        }
    }
}

// ---------------- edge GEMM (K=256) + in-register segmented aggregation ----------------
// Round-6 semantics; K-staging split 64->32 with 80B-padded LDS rows (no swizzle
// needed: stride 5*16B is coprime with the 8 wide banks -> all patterns uniform).
// LDS 25.9KB + launch_bounds(256,3) -> 3 blocks/CU (was 2).
__global__ __launch_bounds__(256, 3) void k_edge_csr(
    const float* __restrict__ ea, const ushort_t* __restrict__ w1bt,
    const float* __restrict__ xw1, const int* __restrict__ elist,
    const int* __restrict__ rowg, const int* __restrict__ posnode,
    const int* __restrict__ rowptr, float* __restrict__ agg)
{
    // padded rows: 32 bf16 cols + 8 pad = 40 shorts (80 B)
    __shared__ __align__(16) ushort_t As[64 * 40];     // ea tile (bf16)
    __shared__ __align__(16) ushort_t Bs[256 * 40];    // W1b tile
    __shared__ int snd[64];                            // dest node per tile row
    const int tid = threadIdx.x;
    const int wave = tid >> 6, lane = tid & 63;
    const int lr = lane & 15, lh = lane >> 4;
    const int p0 = blockIdx.x * 64;

    // row metadata (visible after first barrier)
    if (tid < 64) {
        int p = p0 + tid;
        snd[tid] = (p < N_EDGES) ? posnode[min(p, N_EDGES - 1)] : -1;
    }

    const int sm = tid >> 2;           // A row: 4 threads per row
    const int scq = (tid & 3) << 3;    // 8 f32 cols per thread within 32
    int ps = p0 + sm; if (ps >= N_EDGES) ps = N_EDGES - 1;
    const int es = elist[ps];
    const float* earow = ea + (size_t)es * D;
    const ushort_t* wrow = w1bt + (size_t)tid * D;

    f32x4 acc[4][4];
    #pragma unroll
    for (int i = 0; i < 4; ++i)
        #pragma unroll
        for (int j = 0; j < 4; ++j)
            acc[i][j] = (f32x4){0.f, 0.f, 0.f, 0.f};

    #pragma unroll 1
    for (int kk = 0; kk < 8; ++kk) {
        const int k0 = kk << 5;
        const float4* s = (const float4*)(earow + k0 + scq);
        float4 f0 = s[0], f1 = s[1];
        uint4 av;
        av.x = pk2(f0.x, f0.y); av.y = pk2(f0.z, f0.w);
        av.z = pk2(f1.x, f1.y); av.w = pk2(f1.z, f1.w);
        const uint4* w = (const uint4*)(wrow + k0);
        uint4 w0 = w[0], w1 = w[1], w2 = w[2], w3 = w[3];

        __syncthreads();                       // previous step's LDS reads done
        *(uint4*)&As[sm * 40 + scq] = av;
        {
            ushort_t* bb = &Bs[tid * 40];
            *(uint4*)&bb[ 0] = w0;
            *(uint4*)&bb[ 8] = w1;
            *(uint4*)&bb[16] = w2;
            *(uint4*)&bb[24] = w3;
        }
        __syncthreads();

        {
            const int kb = lh * 8;
            bf16x8 af[4], bfr[4];
            #pragma unroll
            for (int i = 0; i < 4; ++i)
                af[i] = *(const bf16x8*)&As[(i * 16 + lr) * 40 + kb];
            #pragma unroll
            for (int j = 0; j < 4; ++j)
                bfr[j] = *(const bf16x8*)&Bs[(wave * 64 + j * 16 + lr) * 40 + kb];
            #pragma unroll
            for (int i = 0; i < 4; ++i)
                #pragma unroll
                for (int j = 0; j < 4; ++j)
                    acc[i][j] = __builtin_amdgcn_mfma_f32_16x16x32_bf16(af[i], bfr[j], acc[i][j], 0, 0, 0);
        }
    }

    // ---- epilogue 1: add gathered xw1[src], relu, keep in registers ----
    #pragma unroll
    for (int i = 0; i < 4; ++i) {
        #pragma unroll
        for (int r = 0; r < 4; ++r) {
            const int m = i * 16 + lh * 4 + r;
            const bool ok = (p0 + m < N_EDGES);
            const int srw = rowg[min(p0 + m, N_EDGES - 1)];
            const float* xr = xw1 + (size_t)srw * D + wave * 64 + lr;
            #pragma unroll
            for (int j = 0; j < 4; ++j) {
                float v = acc[i][j][r] + xr[j * 16];
                v = v > 0.f ? v : 0.f;
                acc[i][j][r] = ok ? v : 0.f;
            }
        }
    }

    // ---- epilogue 2: block-uniform segment loop, in-register reduce (proven) ----
    int a = 0;
    while (a < 64) {
        const int node = snd[a];
        int b = a + 1;
        while (b < 64 && snd[b] == node) ++b;
        if (node >= 0) {
            float s0 = 0.f, s1 = 0.f, s2 = 0.f, s3 = 0.f;
            #pragma unroll
            for (int i = 0; i < 4; ++i) {
                if (b <= i * 16 || a >= (i + 1) * 16) continue;  // uniform skip
                #pragma unroll
                for (int r = 0; r < 4; ++r) {
                    const int m = i * 16 + lh * 4 + r;
                    const bool in = (m >= a) && (m < b);
                    s0 += in ? acc[i][0][r] : 0.f;
                    s1 += in ? acc[i][1][r] : 0.f;
                    s2 += in ? acc[i][2][r] : 0.f;
                    s3 += in ? acc[i][3][r] : 0.f;
                }
            }
            // fold the 4 lh groups (lanes differ in bits 4,5)
            s0 += __shfl_xor(s0, 16, 64); s0 += __shfl_xor(s0, 32, 64);
            s1 += __shfl_xor(s1, 16, 64); s1 += __shfl_xor(s1, 32, 64);
            s2 += __shfl_xor(s2, 16, 64); s2 += __shfl_xor(s2, 32, 64);
            s3 += __shfl_xor(s3, 16, 64); s3 += __shfl_xor(s3, 32, 64);
            if (lh == 0) {
                const bool interior = (rowptr[node] >= p0) && (rowptr[node + 1] <= p0 + 64);
                float* dst = agg + (size_t)node * D + wave * 64 + lr;
                if (interior) {
                    dst[0]  = s0; dst[16] = s1; dst[32] = s2; dst[48] = s3;
                } else {
                    atomicAdd(&dst[0],  s0); atomicAdd(&dst[16], s1);
                    atomicAdd(&dst[32], s2); atomicAdd(&dst[48], s3);
                }
            }
        }
        a = b;
    }
}

// ---------------- node GEMM ----------------
// out[i][n] = relu( concat(x[i], agg[i]/max(cnt,1)) @ W2 + b2 )
__global__ __launch_bounds__(256) void k_node(
    const ushort_t* __restrict__ xb, const float* __restrict__ agg,
    const int* __restrict__ cnti,
    const ushort_t* __restrict__ w2t, const float* __restrict__ b2,
    float* __restrict__ out)
{
    __shared__ __align__(16) ushort_t As[64 * 64];
    __shared__ __align__(16) ushort_t Bs[256 * 64];
    const int tid = threadIdx.x;
    const int wave = tid >> 6, lane = tid & 63;
    const int lr = lane & 15, lh = lane >> 4;
    const int n0 = blockIdx.x * 64;

    const int sm = tid >> 2;
    const int sc = (tid & 3) << 4;
    int ns = n0 + sm; if (ns >= N_NODES) ns = N_NODES - 1;
    const ushort_t* xrow = xb + (size_t)ns * D;
    const float*    arow = agg + (size_t)ns * D;
    const float     ic   = 1.0f / fmaxf((float)cnti[ns], 1.0f);
    const ushort_t* wrow = w2t + (size_t)tid * TWO_D;
    const int swA = (sm & 7) << 3;
    const int swB = (tid & 7) << 3;

    f32x4 acc[4][4];
    #pragma unroll
    for (int i = 0; i < 4; ++i)
        #pragma unroll
        for (int j = 0; j < 4; ++j)
            acc[i][j] = (f32x4){0.f, 0.f, 0.f, 0.f};

    for (int kk = 0; kk < 8; ++kk) {
        const int k0 = kk << 6;
        uint4 av0, av1;
        if (kk < 4) {
            const uint4* s = (const uint4*)(xrow + k0 + sc);
            av0 = s[0]; av1 = s[1];
        } else {
            const float4* s = (const float4*)(arow + (k0 - D) + sc);
            float4 f0 = s[0], f1 = s[1], f2 = s[2], f3 = s[3];
            f0.x *= ic; f0.y *= ic; f0.z *= ic; f0.w *= ic;
            f1.x *= ic; f1.y *= ic; f1.z *= ic; f1.w *= ic;
            f2.x *= ic; f2.y *= ic; f2.z *= ic; f2.w *= ic;
            f3.x *= ic; f3.y *= ic; f3.z *= ic; f3.w *= ic;
            av0.x = pk2(f0.x, f0.y); av0.y = pk2(f0.z, f0.w);
            av0.z = pk2(f1.x, f1.y); av0.w = pk2(f1.z, f1.w);
            av1.x = pk2(f2.x, f2.y); av1.y = pk2(f2.z, f2.w);
            av1.z = pk2(f3.x, f3.y); av1.w = pk2(f3.z, f3.w);
        }
        const uint4* wsv = (const uint4*)(wrow + k0);
        uint4 w0 = wsv[0], w1 = wsv[1], w2 = wsv[2], w3 = wsv[3];
        uint4 w4 = wsv[4], w5 = wsv[5], w6 = wsv[6], w7 = wsv[7];

        __syncthreads();
        *(uint4*)&As[sm * 64 + ( sc      ^ swA)] = av0;
        *(uint4*)&As[sm * 64 + ((sc + 8) ^ swA)] = av1;
        {
            const int base = tid * 64;
            *(uint4*)&Bs[base + ( 0 ^ swB)] = w0;
            *(uint4*)&Bs[base + ( 8 ^ swB)] = w1;
            *(uint4*)&Bs[base + (16 ^ swB)] = w2;
            *(uint4*)&Bs[base + (24 ^ swB)] = w3;
            *(uint4*)&Bs[base + (32 ^ swB)] = w4;
            *(uint4*)&Bs[base + (40 ^ swB)] = w5;
            *(uint4*)&Bs[base + (48 ^ swB)] = w6;
            *(uint4*)&Bs[base + (56 ^ swB)] = w7;
        }
        __syncthreads();

        #pragma unroll
        for (int kh = 0; kh < 2; ++kh) {
            const int kb = kh * 32 + lh * 8;
            bf16x8 af[4], bfr[4];
            #pragma unroll
            for (int i = 0; i < 4; ++i) {
                int m = i * 16 + lr;
                af[i] = *(const bf16x8*)&As[m * 64 + (kb ^ ((m & 7) << 3))];
            }
            #pragma unroll
            for (int j = 0; j < 4; ++j) {
                int n = wave * 64 + j * 16 + lr;
                bfr[j] = *(const bf16x8*)&Bs[n * 64 + (kb ^ ((n & 7) << 3))];
            }
            #pragma unroll
            for (int i = 0; i < 4; ++i)
                #pragma unroll
                for (int j = 0; j < 4; ++j)
                    acc[i][j] = __builtin_amdgcn_mfma_f32_16x16x32_bf16(af[i], bfr[j], acc[i][j], 0, 0, 0);
        }
    }

    float bv[4];
    #pragma unroll
    for (int j = 0; j < 4; ++j) bv[j] = b2[wave * 64 + j * 16 + lr];
    #pragma unroll
    for (int i = 0; i < 4; ++i) {
        #pragma unroll
        for (int r = 0; r < 4; ++r) {
            int m = i * 16 + lh * 4 + r;
            int node = n0 + m;
            if (node < N_NODES) {
                float* orow = out + (size_t)node * D;
                #pragma unroll
                for (int j = 0; j < 4; ++j) {
                    float v = acc[i][j][r] + bv[j];
                    orow[wave * 64 + j * 16 + lr] = v > 0.f ? v : 0.f;
                }
            }
        }
    }
}

// ---------------- launch ----------------

extern "C" void kernel_launch(void* const* d_in, const int* in_sizes, int n_in,
                              void* d_out, int out_size, void* d_ws, size_t ws_size,
                              hipStream_t stream)
{
    const float* x  = (const float*)d_in[0];
    const int*   ei = (const int*)d_in[1];      // [2*E] int32: rows then cols
    const float* ea = (const float*)d_in[2];
    const float* W1 = (const float*)d_in[5];
    const float* b1 = (const float*)d_in[6];
    const float* W2 = (const float*)d_in[7];
    const float* b2 = (const float*)d_in[8];
    float* out = (float*)d_out;

    const int* rowi = ei;
    const int* coli = ei + N_EDGES;
    char* ws = (char*)d_ws;

    size_t off = 0;
    auto take = [&](size_t bytes) {
        char* p = ws + off;
        off = (off + bytes + 255) & ~(size_t)255;
        return p;
    };

    ushort_t* xb      = (ushort_t*)take((size_t)N_NODES * D * 2);
    ushort_t* w1at    = (ushort_t*)take((size_t)D * D * 2);
    ushort_t* w1bt    = (ushort_t*)take((size_t)D * D * 2);
    ushort_t* w2t     = (ushort_t*)take((size_t)D * TWO_D * 2);
    float*    xw1     = (float*)take((size_t)N_NODES * D * 4);
    float*    agg     = (float*)take((size_t)N_NODES * D * 4);
    int*      cnti    = (int*)take(50016 * 4);
    int*      rowptr  = (int*)take(50016 * 4);
    int*      cursor  = (int*)take(50016 * 4);
    int*      bsum    = (int*)take(256 * 4);
    int*      elist   = (int*)take((size_t)N_EDGES * 4);
    int*      rowg    = (int*)take((size_t)N_EDGES * 4);
    int*      posnode = (int*)take((size_t)N_EDGES * 4);

    const int NB = (N_NODES + 255) / 256;          // 196
    const int EB = (N_EDGES + 255) / 256;          // 1954
    const int NGB = (N_NODES + 63) / 64;           // 782
    const int EGB = (N_EDGES + 63) / 64;           // 7813

    k_cvt_x<<<(N_NODES * D / 8 + 255) / 256, 256, 0, stream>>>(x, xb, N_NODES * D / 8);
    k_wt   <<<D, 256, 0, stream>>>(W1, w1at, D);
    k_wt   <<<D, 256, 0, stream>>>(W1 + (size_t)D * D, w1bt, D);
    k_wt   <<<D, 256, 0, stream>>>(W2, w2t, TWO_D);

    k_zero   <<<49, 256, 0, stream>>>((float*)cnti, 50016 / 4);
    k_count_i<<<EB, 256, 0, stream>>>(coli, cnti);
    k_scan_a <<<NB, 256, 0, stream>>>(cnti, rowptr, bsum);
    k_scan_b <<<1, 256, 0, stream>>>(bsum, NB);
    k_scan_c <<<NB, 256, 0, stream>>>(rowptr, bsum, cursor);
    k_fill   <<<EB, 256, 0, stream>>>(coli, rowi, cursor, elist, rowg);
    k_posnode<<<EB, 256, 0, stream>>>(rowptr, posnode);

    k_xw1    <<<NGB, 256, 0, stream>>>(xb, w1at, b1, xw1);
    k_zero   <<<(N_NODES * D / 4 + 255) / 256, 256, 0, stream>>>(agg, N_NODES * D / 4);
    k_edge_csr<<<EGB, 256, 0, stream>>>(ea, w1bt, xw1, elist, rowg, posnode, rowptr, agg);
    k_node   <<<NGB, 256, 0, stream>>>(xb, agg, cnti, w2t, b2, out);
}